// Round 6
// baseline (86.840 us; speedup 1.0000x reference)
//
#include <hip/hip_runtime.h>

// DepthwiseConv3D: x(8,64,64,32,64) fp32, w(32,3,3,64), b(32,64)
// y[b,h,w,d,c] = sum_{kh,kw} x[b,h+kh-1,w+kw-1,d,c]*w[d,kh,kw,c] + b[d,c]
// float4 strides: c4=1, d=16, w=512, h=32768, b=2097152
//
// R6: persistent h-sliding register window (software pipeline).
// Each thread owns a 4w x 8h strip. 4-row x 6-col register window;
// per row-iter: issue 6 loads for row h+2, FMA row h (rows in regs),
// nt-store 4 outputs. Steady-state load/FMA/store interleave replaces
// the burst->drain->store phase structure of R5. Taps: 2.06/output,
// h-reuse in registers. XCD-chunked swizzle kept (b = blk&7).

typedef float v4 __attribute__((ext_vector_type(4)));

__global__ __launch_bounds__(256, 3) void DepthwiseConv3D_kernel(
    const v4* __restrict__ x, const v4* __restrict__ wgt,
    const v4* __restrict__ bias, v4* __restrict__ y) {
  // Block: b = blk&7 (XCD id); loc = blk>>3: dhi[0] ws[1:4] hs[5:7]
  const int blk = blockIdx.x;
  const int b   = blk & 7;
  const int loc = blk >> 3;
  const int dhi = loc & 1;
  const int ws  = (loc >> 1) & 15;
  const int hs  = loc >> 5;          // 0..7 strips of 8 rows
  const int c4  = threadIdx.x & 15;
  const int dlo = threadIdx.x >> 4;
  const int d   = (dhi << 4) | dlo;
  const int h0  = hs * 8;
  const int w0  = ws * 4;
  const v4 z = (v4)(0.f);

  // float4 index of (b,row,w0,d,c4) = cbase + row*32768
  const int cbase = b * 2097152 + w0 * 512 + d * 16 + c4;
  const bool w_lo = (ws > 0);   // col w0-1 exists
  const bool w_hi = (ws < 15);  // col w0+4 exists

  v4 win[4][6];  // [row slot][w-col]; slot(r) = (r - h0 + 1) & 3

#define LOADROW(r, s)                                                     \
  {                                                                       \
    const int _r = (r);                                                   \
    const bool rok = ((unsigned)_r) < 64u;                                \
    const int rb = cbase + _r * 32768;                                    \
    win[s][0] = (rok && w_lo) ? x[rb - 512] : z;                          \
    win[s][1] = rok ? x[rb] : z;                                          \
    win[s][2] = rok ? x[rb + 512] : z;                                    \
    win[s][3] = rok ? x[rb + 1024] : z;                                   \
    win[s][4] = rok ? x[rb + 1536] : z;                                   \
    win[s][5] = (rok && w_hi) ? x[rb + 2048] : z;                         \
  }

  // Prologue: rows h0-1, h0, h0+1 -> slots 0,1,2
  LOADROW(h0 - 1, 0)
  LOADROW(h0,     1)
  LOADROW(h0 + 1, 2)

  // Weights/bias (L2-resident).
  v4 wt[3][3];
#pragma unroll
  for (int kh = 0; kh < 3; ++kh)
#pragma unroll
    for (int kw = 0; kw < 3; ++kw)
      wt[kh][kw] = wgt[d * 144 + kh * 48 + kw * 16 + c4];
  const v4 bv = bias[d * 16 + c4];

#pragma unroll
  for (int hh = 0; hh < 8; ++hh) {
    // Issue next row's loads first (row h0+hh+2 -> slot (hh+3)&3);
    // they are consumed one iteration later (pipeline depth 1).
    LOADROW(h0 + hh + 2, (hh + 3) & 3)

    v4 acc[4];
#pragma unroll
    for (int i = 0; i < 4; ++i) acc[i] = bv;
#pragma unroll
    for (int kh = 0; kh < 3; ++kh) {
      const int s = (hh + kh) & 3;  // static after unroll
#pragma unroll
      for (int kw = 0; kw < 3; ++kw)
#pragma unroll
        for (int i = 0; i < 4; ++i)
          acc[i] += win[s][i + kw] * wt[kh][kw];
    }

    const int ob = cbase + (h0 + hh) * 32768;
#pragma unroll
    for (int i = 0; i < 4; ++i)
      __builtin_nontemporal_store(acc[i], &y[ob + i * 512]);
  }
#undef LOADROW
}

extern "C" void kernel_launch(void* const* d_in, const int* in_sizes, int n_in,
                              void* d_out, int out_size, void* d_ws, size_t ws_size,
                              hipStream_t stream) {
  const v4* x    = (const v4*)d_in[0];
  const v4* wgt  = (const v4*)d_in[1];
  const v4* bias = (const v4*)d_in[2];
  v4* y          = (v4*)d_out;
  // 8 XCDs x 256 blocks: 8 hs x 16 ws x 2 dhi per batch
  DepthwiseConv3D_kernel<<<2048, 256, 0, stream>>>(x, wgt, bias, y);
}